// Round 5
// baseline (109.738 us; speedup 1.0000x reference)
//
#include <hip/hip_runtime.h>
#include <math.h>

// Problem constants (from reference)
#define BB 8
#define HH 1024
#define DD 4
#define TI2 32           // i-rows per block (2 per thread)
#define NJC 8            // j-chunks
#define JC (HH / NJC)    // 128 j per block
#define INV2PI 0.15915494309189535f

// ws layout: float4 partial[NJC][BB][HH] = 1 MB

__global__ __launch_bounds__(256, 8) void kuramoto_partial(
    const float* __restrict__ theta, const float* __restrict__ A,
    const float* __restrict__ alpha, float* __restrict__ ws)
{
    const int blk = blockIdx.x;          // ((b*32 + it)*NJC + jc)
    const int jc  = blk & (NJC - 1);
    const int it  = (blk >> 3) & 31;
    const int b   = blk >> 8;
    const int i0  = it * TI2;
    const int j0  = jc * JC;
    const int t   = threadIdx.x;
    const int ti  = t >> 4;              // 0..15 -> rows ti and ti+16
    const int tj  = t & 15;              // 0..15

    __shared__ float sAT[JC][TI2 + 1];                        // 16.9 KB, transposed A
    __shared__ float sTh0[JC], sTh1[JC], sTh2[JC], sTh3[JC];  // 2 KB, theta_j in revolutions

    const float* Ab = A + (size_t)b * HH * HH;

    // stage theta_j SoA, pre-scaled to revolutions (threads 0..127, coalesced)
    if (t < JC) {
        const float4 v = ((const float4*)theta)[(size_t)b * HH + j0 + t];
        sTh0[t] = v.x * INV2PI; sTh1[t] = v.y * INV2PI;
        sTh2[t] = v.z * INV2PI; sTh3[t] = v.w * INV2PI;
    }

    // stage transposed A tile: 128 rows x 32 cols, coalesced float4 loads,
    // scalar LDS stores (stride 33: ~2 lanes/bank = free)
    {
        const int r = t >> 3;            // 0..31
        const int c = (t & 7) * 4;       // 0..28
        #pragma unroll
        for (int rr = 0; rr < JC; rr += 32) {
            const int row = rr + r;
            const float4 v = *(const float4*)&Ab[(size_t)(j0 + row) * HH + i0 + c];
            sAT[row][c + 0] = v.x;
            sAT[row][c + 1] = v.y;
            sAT[row][c + 2] = v.z;
            sAT[row][c + 3] = v.w;
        }
    }

    // theta_i for both rows, in revolutions
    float4 thia = ((const float4*)theta)[(size_t)b * HH + i0 + ti];
    float4 thib = ((const float4*)theta)[(size_t)b * HH + i0 + ti + 16];
    thia.x *= INV2PI; thia.y *= INV2PI; thia.z *= INV2PI; thia.w *= INV2PI;
    thib.x *= INV2PI; thib.y *= INV2PI; thib.z *= INV2PI; thib.w *= INV2PI;

    __syncthreads();   // the only barrier

    const float4* Ara = (const float4*)(Ab    + (size_t)(i0 + ti)      * HH + j0);
    const float4* Arb = (const float4*)(Ab    + (size_t)(i0 + ti + 16) * HH + j0);
    const float4* ala = (const float4*)(alpha + (size_t)(i0 + ti)      * HH + j0);
    const float4* alb = (const float4*)(alpha + (size_t)(i0 + ti + 16) * HH + j0);

    float a0 = 0.f, a1 = 0.f, a2 = 0.f, a3 = 0.f;   // row a accum
    float b0 = 0.f, b1 = 0.f, b2 = 0.f, b3 = 0.f;   // row b accum

    #pragma unroll
    for (int s = 0; s < JC / 64; ++s) {          // 2 iters, 4 j's each
        const int q = tj + 16 * s;
        const float4 ad_a = Ara[q];              // coalesced dwordx4 streams
        const float4 ad_b = Arb[q];
        const float4 al_a = ala[q];
        const float4 al_b = alb[q];
        #pragma unroll
        for (int k = 0; k < 4; ++k) {
            const int j = 4 * q + k;
            const float t0 = sTh0[j];            // LDS broadcast (free)
            const float t1 = sTh1[j];
            const float t2 = sTh2[j];
            const float t3 = sTh3[j];
            // row a
            {
                const float alat = fmaxf((&ad_a.x)[k] + sAT[j][ti], 0.0f);
                const float w    = (&al_a.x)[k] * INV2PI;
                a0 += alat * __builtin_amdgcn_sinf(t0 - thia.x - w);
                a1 += alat * __builtin_amdgcn_sinf(t1 - thia.y - w);
                a2 += alat * __builtin_amdgcn_sinf(t2 - thia.z - w);
                a3 += alat * __builtin_amdgcn_sinf(t3 - thia.w - w);
            }
            // row b
            {
                const float alat = fmaxf((&ad_b.x)[k] + sAT[j][ti + 16], 0.0f);
                const float w    = (&al_b.x)[k] * INV2PI;
                b0 += alat * __builtin_amdgcn_sinf(t0 - thib.x - w);
                b1 += alat * __builtin_amdgcn_sinf(t1 - thib.y - w);
                b2 += alat * __builtin_amdgcn_sinf(t2 - thib.z - w);
                b3 += alat * __builtin_amdgcn_sinf(t3 - thib.w - w);
            }
        }
    }

    // reduce over the 16 tj lanes (lane-contiguous groups)
    #pragma unroll
    for (int off = 8; off >= 1; off >>= 1) {
        a0 += __shfl_down(a0, off, 16);
        a1 += __shfl_down(a1, off, 16);
        a2 += __shfl_down(a2, off, 16);
        a3 += __shfl_down(a3, off, 16);
        b0 += __shfl_down(b0, off, 16);
        b1 += __shfl_down(b1, off, 16);
        b2 += __shfl_down(b2, off, 16);
        b3 += __shfl_down(b3, off, 16);
    }

    if (tj == 0) {
        float4 ra; ra.x = a0; ra.y = a1; ra.z = a2; ra.w = a3;
        float4 rb; rb.x = b0; rb.y = b1; rb.z = b2; rb.w = b3;
        float4* w4 = (float4*)ws + ((size_t)jc * BB + b) * HH;
        w4[i0 + ti]      = ra;
        w4[i0 + ti + 16] = rb;
    }
}

__global__ __launch_bounds__(256) void kuramoto_final(
    const float* __restrict__ theta, const float* __restrict__ gamma,
    const float* __restrict__ omega, const float* __restrict__ kappa,
    const float* __restrict__ ws, float* __restrict__ out)
{
    const int idx = blockIdx.x * 256 + threadIdx.x;   // (b,i) flat, 8192 total
    const int i   = idx & (HH - 1);
    const float4* w4 = (const float4*)ws;

    float4 p = w4[idx];
    #pragma unroll
    for (int jc = 1; jc < NJC; ++jc) {
        const float4 q = w4[(size_t)jc * BB * HH + idx];
        p.x += q.x; p.y += q.y; p.z += q.z; p.w += q.w;
    }

    const float4 th = ((const float4*)theta)[idx];
    const float4 om = ((const float4*)omega)[i];
    const float4 kp = ((const float4*)kappa)[i];
    const float  g  = gamma[idx];
    const float  inv = 0.5f / HH;   // K_COUP=1, DT=1, 0.5 from symmetrization fold

    float4 o;
    o.x = th.x + om.x + p.x * inv + kp.x * (g - th.x);
    o.y = th.y + om.y + p.y * inv + kp.y * (g - th.y);
    o.z = th.z + om.z + p.z * inv + kp.z * (g - th.z);
    o.w = th.w + om.w + p.w * inv + kp.w * (g - th.w);
    ((float4*)out)[idx] = o;
}

extern "C" void kernel_launch(void* const* d_in, const int* in_sizes, int n_in,
                              void* d_out, int out_size, void* d_ws, size_t ws_size,
                              hipStream_t stream) {
    const float* theta = (const float*)d_in[0];
    const float* gamma = (const float*)d_in[1];
    const float* A     = (const float*)d_in[2];
    const float* omega = (const float*)d_in[3];
    const float* kappa = (const float*)d_in[4];
    const float* alpha = (const float*)d_in[5];
    float* out = (float*)d_out;
    float* ws  = (float*)d_ws;

    hipLaunchKernelGGL(kuramoto_partial, dim3(BB * (HH / TI2) * NJC), dim3(256), 0, stream,
                       theta, A, alpha, ws);
    hipLaunchKernelGGL(kuramoto_final, dim3(BB * HH / 256), dim3(256), 0, stream,
                       theta, gamma, omega, kappa, ws, out);
}

// Round 6
// 93.249 us; speedup vs baseline: 1.1768x; 1.1768x over previous
//
#include <hip/hip_runtime.h>
#include <math.h>

// Problem constants (from reference)
#define BB 8
#define HH 1024
#define DD 4
#define TI 16            // i-rows per block
#define NJC 8            // j-chunks
#define JC (HH / NJC)    // 128 j per block
#define INV2PI 0.15915494309189535f

// ws layout: float4 partial[NJC][BB][HH] = 1 MB

__global__ __launch_bounds__(256, 8) void kuramoto_partial(
    const float* __restrict__ theta, const float* __restrict__ A,
    const float* __restrict__ alpha, float* __restrict__ ws)
{
    const int blk = blockIdx.x;          // ((b*64 + it)*NJC + jc)
    const int jc  = blk & (NJC - 1);
    const int it  = (blk >> 3) & 63;
    const int b   = blk >> 9;
    const int i0  = it * TI;
    const int j0  = jc * JC;
    const int t   = threadIdx.x;
    const int ti  = t >> 4;              // 0..15
    const int tj  = t & 15;              // 0..15

    __shared__ float sTh0[JC], sTh1[JC], sTh2[JC], sTh3[JC];  // theta_j planes, revolutions (2 KB)
    __shared__ float sAT[JC][TI + 1];                         // A[b, j0+r, i0+c] transposed (8.7 KB)

    const float* Ab = A + (size_t)b * HH * HH;

    // stage theta_j SoA, pre-scaled to revolutions (threads 0..127, coalesced float4)
    if (t < JC) {
        const float4 v = ((const float4*)theta)[(size_t)b * HH + j0 + t];
        sTh0[t] = v.x * INV2PI; sTh1[t] = v.y * INV2PI;
        sTh2[t] = v.z * INV2PI; sTh3[t] = v.w * INV2PI;
    }

    // stage transposed A tile: 128 rows x 16 cols, coalesced float4 loads,
    // scalar LDS stores (stride 17: exactly 2 lanes/bank = free)
    {
        const int r = t >> 2;            // 0..63
        const int c = (t & 3) * 4;       // 0,4,8,12
        #pragma unroll
        for (int rr = 0; rr < JC; rr += 64) {
            const int row = rr + r;
            const float4 v = *(const float4*)&Ab[(size_t)(j0 + row) * HH + i0 + c];
            sAT[row][c + 0] = v.x;
            sAT[row][c + 1] = v.y;
            sAT[row][c + 2] = v.z;
            sAT[row][c + 3] = v.w;
        }
    }

    // theta_i in revolutions
    float4 thi = ((const float4*)theta)[(size_t)b * HH + i0 + ti];
    thi.x *= INV2PI; thi.y *= INV2PI; thi.z *= INV2PI; thi.w *= INV2PI;

    __syncthreads();   // the only barrier

    const float4* Arow4  = (const float4*)(Ab    + (size_t)(i0 + ti) * HH + j0);
    const float4* alrow4 = (const float4*)(alpha + (size_t)(i0 + ti) * HH + j0);

    float a0 = 0.f, a1 = 0.f, a2 = 0.f, a3 = 0.f;

    #pragma unroll
    for (int s = 0; s < JC / 64; ++s) {          // 2 iters, 4 j's each
        const int q = tj + 16 * s;
        const float4 ad = Arow4[q];              // coalesced dwordx4 (HBM stream)
        const float4 al = alrow4[q];             // coalesced dwordx4 (L3-resident)
        #pragma unroll
        for (int k = 0; k < 4; ++k) {
            const int j = 4 * q + k;
            // alat: 0.5 folded into finalize constant
            const float alat = fmaxf((&ad.x)[k] + sAT[j][ti], 0.0f);
            const float w    = (&al.x)[k] * INV2PI;       // alpha in revolutions
            const float z0 = thi.x + w, z1 = thi.y + w;
            const float z2 = thi.z + w, z3 = thi.w + w;
            // sTh reads: all 16 ti-groups hit the same address -> LDS broadcast (free)
            a0 += alat * __builtin_amdgcn_sinf(sTh0[j] - z0);
            a1 += alat * __builtin_amdgcn_sinf(sTh1[j] - z1);
            a2 += alat * __builtin_amdgcn_sinf(sTh2[j] - z2);
            a3 += alat * __builtin_amdgcn_sinf(sTh3[j] - z3);
        }
    }

    // reduce over the 16 tj lanes (ti groups are lane-contiguous in a wave)
    #pragma unroll
    for (int off = 8; off >= 1; off >>= 1) {
        a0 += __shfl_down(a0, off, 16);
        a1 += __shfl_down(a1, off, 16);
        a2 += __shfl_down(a2, off, 16);
        a3 += __shfl_down(a3, off, 16);
    }

    if (tj == 0) {
        float4 r; r.x = a0; r.y = a1; r.z = a2; r.w = a3;
        ((float4*)ws)[((size_t)jc * BB + b) * HH + i0 + ti] = r;
    }
}

__global__ __launch_bounds__(256) void kuramoto_final(
    const float* __restrict__ theta, const float* __restrict__ gamma,
    const float* __restrict__ omega, const float* __restrict__ kappa,
    const float* __restrict__ ws, float* __restrict__ out)
{
    const int idx = blockIdx.x * 256 + threadIdx.x;   // (b,i) flat, 8192 total
    const int i   = idx & (HH - 1);
    const float4* w4 = (const float4*)ws;

    float4 p = w4[idx];
    #pragma unroll
    for (int jc = 1; jc < NJC; ++jc) {
        const float4 q = w4[(size_t)jc * BB * HH + idx];
        p.x += q.x; p.y += q.y; p.z += q.z; p.w += q.w;
    }

    const float4 th = ((const float4*)theta)[idx];
    const float4 om = ((const float4*)omega)[i];
    const float4 kp = ((const float4*)kappa)[i];
    const float  g  = gamma[idx];
    const float  inv = 0.5f / HH;   // K_COUP=1, DT=1, 0.5 from symmetrization fold

    float4 o;
    o.x = th.x + om.x + p.x * inv + kp.x * (g - th.x);
    o.y = th.y + om.y + p.y * inv + kp.y * (g - th.y);
    o.z = th.z + om.z + p.z * inv + kp.z * (g - th.z);
    o.w = th.w + om.w + p.w * inv + kp.w * (g - th.w);
    ((float4*)out)[idx] = o;
}

extern "C" void kernel_launch(void* const* d_in, const int* in_sizes, int n_in,
                              void* d_out, int out_size, void* d_ws, size_t ws_size,
                              hipStream_t stream) {
    const float* theta = (const float*)d_in[0];
    const float* gamma = (const float*)d_in[1];
    const float* A     = (const float*)d_in[2];
    const float* omega = (const float*)d_in[3];
    const float* kappa = (const float*)d_in[4];
    const float* alpha = (const float*)d_in[5];
    float* out = (float*)d_out;
    float* ws  = (float*)d_ws;

    hipLaunchKernelGGL(kuramoto_partial, dim3(BB * (HH / TI) * NJC), dim3(256), 0, stream,
                       theta, A, alpha, ws);
    hipLaunchKernelGGL(kuramoto_final, dim3(BB * HH / 256), dim3(256), 0, stream,
                       theta, gamma, omega, kappa, ws, out);
}